// Round 2
// baseline (369.315 us; speedup 1.0000x reference)
//
#include <hip/hip_runtime.h>

#define NN 100000
#define NE 1600000
#define NBUCK 1563     // ceil(NN/64)
#define NBH 256        // histogram/placement blocks
#define CHUNK 6250     // NE/NBH
#define NBXB 12500     // NN*32/256 blocks for x->bf16
#define NBG 1563       // ceil(NN/64) for fused GEMM

// ws layout (bytes):
//   xb:    0           (25,600,000)  bf16 x                      [live: k_pre..k_agg1]
//   P:     25,600,000  (25,600,000)  per-node 256B slot          [live: k_agg1..k_agg2]
//     ghist: 25,600,000 (1,600,512)  [NBH][NBUCK]  dead after k_scanB   (overlaps P)
//     boffT: 27,200,512 (1,600,512)  [NBH][NBUCK]  (TRANSPOSED) dead after k_place
//     tot:   28,801,024 (6,252)      dead after k_binC                  (overlaps P)
//     bbase: 28,807,276 (6,252)      dead after k_binC                  (overlaps P)
//   row_start: 51,200,000 ((NN+1)*4)
//   dinv:  51,600,004  (400,000)
//   csr:   52,000,004  (6,400,000)   node-sorted src-only
//   ebuf:  58,400,004  (6,400,000)   bucket-sorted packed; dead after k_binC
// total 64.8 MB. No memsets needed.

typedef short bf16x8 __attribute__((ext_vector_type(8)));
typedef float f32x4  __attribute__((ext_vector_type(4)));
typedef float f32x2  __attribute__((ext_vector_type(2)));

__device__ __forceinline__ float b2f(unsigned short u) {
    return __uint_as_float(((unsigned int)u) << 16);
}
__device__ __forceinline__ unsigned short f2b(float f) {
    unsigned int x = __float_as_uint(f);
    x += 0x7FFFu + ((x >> 16) & 1u);   // RNE
    return (unsigned short)(x >> 16);
}

// ---- fused: x->bf16 (blocks [0,NBXB)) + bucket histogram (blocks [NBXB,NBXB+NBH)) ----
__global__ __launch_bounds__(256) void k_pre(const float* __restrict__ x,
                                             unsigned short* __restrict__ xb,
                                             const int* __restrict__ dst,
                                             int* __restrict__ ghist) {
    int b = blockIdx.x;
    if (b < NBXB) {
        int id = b * 256 + threadIdx.x;
        float4 v = ((const float4*)x)[id];
        ushort4 o;
        o.x = f2b(v.x); o.y = f2b(v.y); o.z = f2b(v.z); o.w = f2b(v.w);
        ((ushort4*)xb)[id] = o;
        return;
    }
    __shared__ int h[NBUCK];
    int tid = threadIdx.x;
    int i = b - NBXB;
    for (int k = tid; k < NBUCK; k += 256) h[k] = 0;
    __syncthreads();
    int e0 = i * CHUNK;
    for (int e = e0 + tid; e < e0 + CHUNK; e += 256) {
        unsigned d = (unsigned)dst[e];
        if (d < NN) atomicAdd(&h[d >> 6], 1);
    }
    __syncthreads();
    for (int k = tid; k < NBUCK; k += 256) ghist[i * NBUCK + k] = h[k];
}

// ---- per-bucket scan over blocks: boffT[i][k] (coalesced writes), tot[k] ----
__global__ __launch_bounds__(256) void k_scanB(const int* __restrict__ ghist,
                                               int* __restrict__ boffT,
                                               int* __restrict__ tot) {
    int k = blockIdx.x * 256 + threadIdx.x;
    if (k >= NBUCK) return;
    int sum = 0;
#pragma unroll 8
    for (int i = 0; i < NBH; ++i) {
        int c = ghist[i * NBUCK + k];
        boffT[i * NBUCK + k] = sum;      // [i][k]: lanes consecutive -> coalesced
        sum += c;
    }
    tot[k] = sum;
}

// ---- exclusive scan of bucket totals -> bbase ----
__global__ __launch_bounds__(256) void k_scanT(const int* __restrict__ tot,
                                               int* __restrict__ bbase) {
    __shared__ int s[256];
    int tid = threadIdx.x;
    int k0 = tid * 7;
    int v[7]; int S = 0;
#pragma unroll
    for (int q = 0; q < 7; ++q) {
        int k = k0 + q;
        v[q] = (k < NBUCK) ? tot[k] : 0;
        S += v[q];
    }
    s[tid] = S;
    __syncthreads();
    for (int off = 1; off < 256; off <<= 1) {
        int t = (tid >= off) ? s[tid - off] : 0;
        __syncthreads();
        s[tid] += t;
        __syncthreads();
    }
    int run = s[tid] - S;   // exclusive
#pragma unroll
    for (int q = 0; q < 7; ++q) {
        int k = k0 + q;
        if (k < NBUCK) { bbase[k] = run; run += v[q]; }
    }
}

// ---- placement: bucket-sorted packed records via LDS cursors (no global atomics) ----
__global__ __launch_bounds__(256) void k_place(const int* __restrict__ src,
                                               const int* __restrict__ dst,
                                               const int* __restrict__ bbase,
                                               const int* __restrict__ boffT,
                                               int* __restrict__ ebuf) {
    __shared__ int cur[NBUCK];
    int tid = threadIdx.x, i = blockIdx.x;
    for (int k = tid; k < NBUCK; k += 256)
        cur[k] = bbase[k] + boffT[i * NBUCK + k];   // [i][k]: coalesced
    __syncthreads();
    int e0 = i * CHUNK;
    for (int e = e0 + tid; e < e0 + CHUNK; e += 256) {
        unsigned d = (unsigned)dst[e];
        if (d >= NN) continue;
        unsigned s = (unsigned)src[e];
        if (s >= NN) s = 0;
        int pos = atomicAdd(&cur[d >> 6], 1);
        ebuf[pos] = (int)(s | ((d & 63u) << 17));
    }
}

// ---- per-bucket: count per node, write row_start/dinv, place src-only csr ----
__global__ __launch_bounds__(256) void k_binC(const int* __restrict__ bbase,
                                              const int* __restrict__ tot,
                                              const int* __restrict__ ebuf,
                                              int* __restrict__ row_start,
                                              float* __restrict__ dinv,
                                              int* __restrict__ csr) {
    __shared__ int cnt[64], excl[64], cur[64];
    int b = blockIdx.x, tid = threadIdx.x;
    int n0 = b * 64;
    int base = bbase[b], end = base + tot[b];
    if (tid < 64) cnt[tid] = 0;
    __syncthreads();
    for (int i = base + tid; i < end; i += 256)
        atomicAdd(&cnt[((unsigned)ebuf[i]) >> 17], 1);
    __syncthreads();
    if (tid == 0) {
        int run = 0;
        for (int t = 0; t < 64; ++t) { excl[t] = run; run += cnt[t]; }
    }
    __syncthreads();
    if (tid < 64) {
        int node = n0 + tid;
        if (node < NN) {
            row_start[node] = base + excl[tid];
            dinv[node] = rsqrtf((float)cnt[tid] + 1.0f);
        }
        cur[tid] = base + excl[tid];
    }
    if (b == NBUCK - 1 && tid == 0) row_start[NN] = end;
    __syncthreads();
    for (int i = base + tid; i < end; i += 256) {
        unsigned rec = (unsigned)ebuf[i];
        int pos = atomicAdd(&cur[rec >> 17], 1);
        csr[pos] = (int)(rec & 0x1FFFFu);
    }
}

// ---- layer-1 aggregate: 2 nodes per wave (half-wave = 32 lanes x 8B covers 256B row),
//      16 edges in flight per wave, scalar csr/dinv loads, packed fma ----
__global__ __launch_bounds__(256) void k_agg1(const unsigned short* __restrict__ xb,
                                              const float* __restrict__ dinv,
                                              const int* __restrict__ row_start,
                                              const int* __restrict__ csr,
                                              char* __restrict__ P) {
    int w = threadIdx.x >> 6;
    int nA = __builtin_amdgcn_readfirstlane(blockIdx.x * 8 + w * 2);  // wave-uniform
    int lane = threadIdx.x & 63;
    int half = lane >> 5, l32 = lane & 31;
    int b0 = row_start[nA];
    int m0 = row_start[nA + 1];
    int e0 = row_start[nA + 2];
    int degA = m0 - b0, degB = e0 - m0;
    float dvA = dinv[nA], dvB = dinv[nA + 1];
    float dv = half ? dvB : dvA;
    float sn = dv * dv;
    int n = nA + half;
    const uint2* xw2 = (const uint2*)xb;            // 32 uint2 per 256B row
    uint2 sv = xw2[n * 32 + l32];
    f32x2 a0, a1;
    a0.x = __uint_as_float(sv.x << 16) * sn;
    a0.y = __uint_as_float(sv.x & 0xFFFF0000u) * sn;
    a1.x = __uint_as_float(sv.y << 16) * sn;
    a1.y = __uint_as_float(sv.y & 0xFFFF0000u) * sn;

    int minD = min(degA, degB), steps = max(degA, degB);
    int k = 0;
    for (; k + 8 <= minD; k += 8) {                 // both halves full: contiguous s_loads
        int sA[8], sB[8], sq[8]; float wgt[8]; uint2 v[8];
#pragma unroll
        for (int q = 0; q < 8; ++q) { sA[q] = csr[b0 + k + q]; sB[q] = csr[m0 + k + q]; }
#pragma unroll
        for (int q = 0; q < 8; ++q) {
            float wA = dinv[sA[q]], wB = dinv[sB[q]];   // scalar loads
            wgt[q] = (half ? wB : wA) * dv;
            sq[q] = half ? sB[q] : sA[q];
        }
#pragma unroll
        for (int q = 0; q < 8; ++q) v[q] = xw2[sq[q] * 32 + l32];   // 8 dual-row gathers
#pragma unroll
        for (int q = 0; q < 8; ++q) {
            f32x2 xv, wv;
            wv.x = wgt[q]; wv.y = wgt[q];
            xv.x = __uint_as_float(v[q].x << 16);
            xv.y = __uint_as_float(v[q].x & 0xFFFF0000u);
            a0 = __builtin_elementwise_fma(xv, wv, a0);
            xv.x = __uint_as_float(v[q].y << 16);
            xv.y = __uint_as_float(v[q].y & 0xFFFF0000u);
            a1 = __builtin_elementwise_fma(xv, wv, a1);
        }
    }
    for (; k < steps; k += 8) {                     // clamped tail (w=0 neutralizes)
        int sA[8], sB[8], sq[8]; float wgt[8]; uint2 v[8];
#pragma unroll
        for (int q = 0; q < 8; ++q) {
            int cA = max(min(k + q, degA - 1), 0);
            int cB = max(min(k + q, degB - 1), 0);
            sA[q] = csr[b0 + cA] & 131071;
            sB[q] = csr[m0 + cB] & 131071;
            float wA = (k + q < degA) ? dinv[sA[q]] : 0.f;
            float wB = (k + q < degB) ? dinv[sB[q]] : 0.f;
            wgt[q] = (half ? wB : wA) * dv;
            sq[q] = half ? sB[q] : sA[q];
        }
#pragma unroll
        for (int q = 0; q < 8; ++q) v[q] = xw2[sq[q] * 32 + l32];
#pragma unroll
        for (int q = 0; q < 8; ++q) {
            f32x2 xv, wv;
            wv.x = wgt[q]; wv.y = wgt[q];
            xv.x = __uint_as_float(v[q].x << 16);
            xv.y = __uint_as_float(v[q].x & 0xFFFF0000u);
            a0 = __builtin_elementwise_fma(xv, wv, a0);
            xv.x = __uint_as_float(v[q].y << 16);
            xv.y = __uint_as_float(v[q].y & 0xFFFF0000u);
            a1 = __builtin_elementwise_fma(xv, wv, a1);
        }
    }
    uint2 o;
    o.x = (unsigned)f2b(a0.x) | ((unsigned)f2b(a0.y) << 16);
    o.y = (unsigned)f2b(a1.x) | ((unsigned)f2b(a1.y) << 16);
    ((uint2*)(P + (size_t)n * 256))[l32] = o;
}

// ---- fused GEMM1+GEMM2 (MFMA): t2 = bf16( relu(agg@W1+b1) @ W2 ), in-place ----
__global__ __launch_bounds__(256) void k_gemm12(const float* __restrict__ W1,
                                                const float* __restrict__ b1,
                                                const float* __restrict__ W2,
                                                char* __restrict__ P) {
    __shared__ short Wl1[16384];                    // [ct8][ks4][lane64][j8]
    __shared__ short Wl2[8192];                     // [ct4][ks4][lane64][j8]
    __shared__ __align__(16) short Cl[4][16][128];
    const int tid = threadIdx.x;
    const int w = tid >> 6, lane = tid & 63;
    const int r0 = blockIdx.x * 64;

    for (int i = tid; i < 16384; i += 256) {
        int j = i & 7, l = (i >> 3) & 63, ks = (i >> 9) & 3, ct = i >> 11;
        int k = ks * 32 + ((l >> 4) << 3) + j;
        int c = ct * 16 + (l & 15);
        Wl1[i] = (short)f2b(W1[k * 128 + c]);
    }
    for (int i = tid; i < 8192; i += 256) {
        int j = i & 7, l = (i >> 3) & 63, ks = (i >> 9) & 3, ct = i >> 11;
        int k = ks * 32 + ((l >> 4) << 3) + j;
        int c = ct * 16 + (l & 15);
        Wl2[i] = (short)f2b(W2[k * 64 + c]);
    }
    __syncthreads();

    const int m = r0 + w * 16 + (lane & 15);
    const int quad = lane >> 4;
    const bool mok = (m < NN);
    bf16x8 a[4];
#pragma unroll
    for (int ks = 0; ks < 4; ++ks) {
        if (mok) a[ks] = *(const bf16x8*)(P + (size_t)m * 256 + (ks * 32 + quad * 8) * 2);
        else     a[ks] = bf16x8{0,0,0,0,0,0,0,0};
    }
#pragma unroll
    for (int ct = 0; ct < 8; ++ct) {
        f32x4 c = {0.f, 0.f, 0.f, 0.f};
#pragma unroll
        for (int ks = 0; ks < 4; ++ks) {
            bf16x8 b = *(const bf16x8*)&Wl1[((ct * 4 + ks) * 64 + lane) * 8];
            c = __builtin_amdgcn_mfma_f32_16x16x32_bf16(a[ks], b, c, 0, 0, 0);
        }
        int col = ct * 16 + (lane & 15);
        float bias = b1[col];
#pragma unroll
        for (int r = 0; r < 4; ++r)
            Cl[w][quad * 4 + r][col] = (short)f2b(fmaxf(c[r] + bias, 0.f));
    }
    __syncthreads();
    bf16x8 a2[4];
#pragma unroll
    for (int ks = 0; ks < 4; ++ks)
        a2[ks] = *(const bf16x8*)&Cl[w][lane & 15][ks * 32 + quad * 8];
    __syncthreads();
    short* Ct = &Cl[0][0][0];   // [64 rows][64 cols]
#pragma unroll
    for (int ct = 0; ct < 4; ++ct) {
        f32x4 c = {0.f, 0.f, 0.f, 0.f};
#pragma unroll
        for (int ks = 0; ks < 4; ++ks) {
            bf16x8 b = *(const bf16x8*)&Wl2[((ct * 4 + ks) * 64 + lane) * 8];
            c = __builtin_amdgcn_mfma_f32_16x16x32_bf16(a2[ks], b, c, 0, 0, 0);
        }
        int col = ct * 16 + (lane & 15);
#pragma unroll
        for (int r = 0; r < 4; ++r)
            Ct[(w * 16 + quad * 4 + r) * 64 + col] = (short)f2b(c[r]);
    }
    __syncthreads();
    for (int it = 0; it < 8; ++it) {
        int row = it * 2 + (lane >> 5), u = lane & 31;
        int node = r0 + w * 16 + row;
        if (node < NN)
            *(unsigned int*)(P + (size_t)node * 256 + u * 4) =
                ((const unsigned int*)&Ct[(w * 16 + row) * 64])[u];
    }
}

// ---- layer-2 aggregate + epilogue: 2 nodes per wave (half-wave = 32 lanes x 4B = 128B row) ----
__global__ __launch_bounds__(256) void k_agg2(const float* __restrict__ dinv,
                                              const int* __restrict__ row_start,
                                              const int* __restrict__ csr,
                                              const char* __restrict__ P,
                                              const float* __restrict__ b2,
                                              float* __restrict__ outp) {
    int w = threadIdx.x >> 6;
    int nA = __builtin_amdgcn_readfirstlane(blockIdx.x * 8 + w * 2);
    int lane = threadIdx.x & 63;
    int half = lane >> 5, l32 = lane & 31;
    int b0 = row_start[nA];
    int m0 = row_start[nA + 1];
    int e0 = row_start[nA + 2];
    int degA = m0 - b0, degB = e0 - m0;
    float dvA = dinv[nA], dvB = dinv[nA + 1];
    float dv = half ? dvB : dvA;
    float sn = dv * dv;
    int n = nA + half;
    const unsigned int* Pw = (const unsigned int*)P;    // row stride 64 uints (256B slot)
    unsigned int sv = Pw[n * 64 + l32];
    f32x2 acc;
    acc.x = __uint_as_float(sv << 16) * sn;
    acc.y = __uint_as_float(sv & 0xFFFF0000u) * sn;

    int minD = min(degA, degB), steps = max(degA, degB);
    int k = 0;
    for (; k + 8 <= minD; k += 8) {
        int sA[8], sB[8], sq[8]; float wgt[8]; unsigned int v[8];
#pragma unroll
        for (int q = 0; q < 8; ++q) { sA[q] = csr[b0 + k + q]; sB[q] = csr[m0 + k + q]; }
#pragma unroll
        for (int q = 0; q < 8; ++q) {
            float wA = dinv[sA[q]], wB = dinv[sB[q]];
            wgt[q] = (half ? wB : wA) * dv;
            sq[q] = half ? sB[q] : sA[q];
        }
#pragma unroll
        for (int q = 0; q < 8; ++q) v[q] = Pw[sq[q] * 64 + l32];
#pragma unroll
        for (int q = 0; q < 8; ++q) {
            f32x2 xv, wv;
            wv.x = wgt[q]; wv.y = wgt[q];
            xv.x = __uint_as_float(v[q] << 16);
            xv.y = __uint_as_float(v[q] & 0xFFFF0000u);
            acc = __builtin_elementwise_fma(xv, wv, acc);
        }
    }
    for (; k < steps; k += 8) {
        int sA[8], sB[8], sq[8]; float wgt[8]; unsigned int v[8];
#pragma unroll
        for (int q = 0; q < 8; ++q) {
            int cA = max(min(k + q, degA - 1), 0);
            int cB = max(min(k + q, degB - 1), 0);
            sA[q] = csr[b0 + cA] & 131071;
            sB[q] = csr[m0 + cB] & 131071;
            float wA = (k + q < degA) ? dinv[sA[q]] : 0.f;
            float wB = (k + q < degB) ? dinv[sB[q]] : 0.f;
            wgt[q] = (half ? wB : wA) * dv;
            sq[q] = half ? sB[q] : sA[q];
        }
#pragma unroll
        for (int q = 0; q < 8; ++q) v[q] = Pw[sq[q] * 64 + l32];
#pragma unroll
        for (int q = 0; q < 8; ++q) {
            f32x2 xv, wv;
            wv.x = wgt[q]; wv.y = wgt[q];
            xv.x = __uint_as_float(v[q] << 16);
            xv.y = __uint_as_float(v[q] & 0xFFFF0000u);
            acc = __builtin_elementwise_fma(xv, wv, acc);
        }
    }
    float2 bb = ((const float2*)b2)[l32];
    float2 o;
    o.x = acc.x + bb.x;
    o.y = acc.y + bb.y;
    ((float2*)outp)[(size_t)n * 32 + l32] = o;
}

extern "C" void kernel_launch(void* const* d_in, const int* in_sizes, int n_in,
                              void* d_out, int out_size, void* d_ws, size_t ws_size,
                              hipStream_t stream) {
    const float* x  = (const float*)d_in[0];
    const int*   ei = (const int*)d_in[1];
    const float* W1 = (const float*)d_in[2];
    const float* b1 = (const float*)d_in[3];
    const float* W2 = (const float*)d_in[4];
    const float* b2 = (const float*)d_in[5];
    float* out = (float*)d_out;
    const int* src = ei;
    const int* dst = ei + NE;

    char* ws = (char*)d_ws;
    unsigned short* xb        = (unsigned short*)(ws + 0);
    char*           P         = ws + 25600000;
    int*            ghist     = (int*)(ws + 25600000);   // overlaps P (dead first)
    int*            boffT     = (int*)(ws + 27200512);
    int*            tot       = (int*)(ws + 28801024);
    int*            bbase     = (int*)(ws + 28807276);
    int*            row_start = (int*)(ws + 51200000);
    float*          dinv      = (float*)(ws + 51600004);
    int*            csr       = (int*)(ws + 52000004);
    int*            ebuf      = (int*)(ws + 58400004);

    k_pre  <<<NBXB + NBH, 256, 0, stream>>>(x, xb, dst, ghist);
    k_scanB<<<(NBUCK + 255) / 256, 256, 0, stream>>>(ghist, boffT, tot);
    k_scanT<<<1, 256, 0, stream>>>(tot, bbase);
    k_place<<<NBH, 256, 0, stream>>>(src, dst, bbase, boffT, ebuf);
    k_binC <<<NBUCK, 256, 0, stream>>>(bbase, tot, ebuf, row_start, dinv, csr);

    k_agg1  <<<NN / 8, 256, 0, stream>>>(xb, dinv, row_start, csr, P);
    k_gemm12<<<NBG, 256, 0, stream>>>(W1, b1, W2, P);
    k_agg2  <<<NN / 8, 256, 0, stream>>>(dinv, row_start, csr, P, b2, out);
}

// Round 3
// 345.180 us; speedup vs baseline: 1.0699x; 1.0699x over previous
//
#include <hip/hip_runtime.h>

#define NN 100000
#define NE 1600000
#define NBUCK 1563     // ceil(NN/64)
#define NBH 256        // histogram/placement blocks
#define CHUNK 6250     // NE/NBH
#define NBXB 12500     // NN*32/256 blocks for x->bf16
#define NBG 1563       // ceil(NN/64) for fused GEMM

// ws layout (bytes):
//   xb:    0           (25,600,000)  bf16 x                      [live: k_pre..k_agg1]
//   P:     25,600,000  (25,600,000)  per-node 256B slot          [live: k_agg1..k_agg2]
//     ghist: 25,600,000 (1,600,512)  [NBH][NBUCK]  dead after k_scanB   (overlaps P)
//     boffT: 27,200,512 (1,600,512)  [NBH][NBUCK]  (TRANSPOSED) dead after k_place
//     tot:   28,801,024 (6,252)      dead after k_binC                  (overlaps P)
//     bbase: 28,807,276 (6,252)      dead after k_binC                  (overlaps P)
//   row_start: 51,200,000 ((NN+1)*4)
//   dinv:  51,600,004  (400,000)
//   csr:   52,000,004  (6,400,000)   node-sorted src-only
//   ebuf:  58,400,004  (6,400,000)   bucket-sorted packed; dead after k_binC
// total 64.8 MB. No memsets needed.

typedef short bf16x8 __attribute__((ext_vector_type(8)));
typedef float f32x4  __attribute__((ext_vector_type(4)));
typedef float f32x2  __attribute__((ext_vector_type(2)));

__device__ __forceinline__ float b2f(unsigned short u) {
    return __uint_as_float(((unsigned int)u) << 16);
}
__device__ __forceinline__ unsigned short f2b(float f) {
    unsigned int x = __float_as_uint(f);
    x += 0x7FFFu + ((x >> 16) & 1u);   // RNE
    return (unsigned short)(x >> 16);
}

// ---- fused: x->bf16 (blocks [0,NBXB)) + bucket histogram (blocks [NBXB,NBXB+NBH)) ----
__global__ __launch_bounds__(256) void k_pre(const float* __restrict__ x,
                                             unsigned short* __restrict__ xb,
                                             const int* __restrict__ dst,
                                             int* __restrict__ ghist) {
    int b = blockIdx.x;
    if (b < NBXB) {
        int id = b * 256 + threadIdx.x;
        float4 v = ((const float4*)x)[id];
        ushort4 o;
        o.x = f2b(v.x); o.y = f2b(v.y); o.z = f2b(v.z); o.w = f2b(v.w);
        ((ushort4*)xb)[id] = o;
        return;
    }
    __shared__ int h[NBUCK];
    int tid = threadIdx.x;
    int i = b - NBXB;
    for (int k = tid; k < NBUCK; k += 256) h[k] = 0;
    __syncthreads();
    int e0 = i * CHUNK;
    for (int e = e0 + tid; e < e0 + CHUNK; e += 256) {
        unsigned d = (unsigned)dst[e];
        if (d < NN) atomicAdd(&h[d >> 6], 1);
    }
    __syncthreads();
    for (int k = tid; k < NBUCK; k += 256) ghist[i * NBUCK + k] = h[k];
}

// ---- per-bucket scan over blocks: boffT[i][k] (coalesced writes), tot[k] ----
__global__ __launch_bounds__(256) void k_scanB(const int* __restrict__ ghist,
                                               int* __restrict__ boffT,
                                               int* __restrict__ tot) {
    int k = blockIdx.x * 256 + threadIdx.x;
    if (k >= NBUCK) return;
    int sum = 0;
#pragma unroll 8
    for (int i = 0; i < NBH; ++i) {
        int c = ghist[i * NBUCK + k];
        boffT[i * NBUCK + k] = sum;      // [i][k]: lanes consecutive -> coalesced
        sum += c;
    }
    tot[k] = sum;
}

// ---- exclusive scan of bucket totals -> bbase ----
__global__ __launch_bounds__(256) void k_scanT(const int* __restrict__ tot,
                                               int* __restrict__ bbase) {
    __shared__ int s[256];
    int tid = threadIdx.x;
    int k0 = tid * 7;
    int v[7]; int S = 0;
#pragma unroll
    for (int q = 0; q < 7; ++q) {
        int k = k0 + q;
        v[q] = (k < NBUCK) ? tot[k] : 0;
        S += v[q];
    }
    s[tid] = S;
    __syncthreads();
    for (int off = 1; off < 256; off <<= 1) {
        int t = (tid >= off) ? s[tid - off] : 0;
        __syncthreads();
        s[tid] += t;
        __syncthreads();
    }
    int run = s[tid] - S;   // exclusive
#pragma unroll
    for (int q = 0; q < 7; ++q) {
        int k = k0 + q;
        if (k < NBUCK) { bbase[k] = run; run += v[q]; }
    }
}

// ---- placement: bucket-sorted packed records via LDS cursors (no global atomics) ----
__global__ __launch_bounds__(256) void k_place(const int* __restrict__ src,
                                               const int* __restrict__ dst,
                                               const int* __restrict__ bbase,
                                               const int* __restrict__ boffT,
                                               int* __restrict__ ebuf) {
    __shared__ int cur[NBUCK];
    int tid = threadIdx.x, i = blockIdx.x;
    for (int k = tid; k < NBUCK; k += 256)
        cur[k] = bbase[k] + boffT[i * NBUCK + k];   // [i][k]: coalesced
    __syncthreads();
    int e0 = i * CHUNK;
    for (int e = e0 + tid; e < e0 + CHUNK; e += 256) {
        unsigned d = (unsigned)dst[e];
        if (d >= NN) continue;
        unsigned s = (unsigned)src[e];
        if (s >= NN) s = 0;
        int pos = atomicAdd(&cur[d >> 6], 1);
        ebuf[pos] = (int)(s | ((d & 63u) << 17));
    }
}

// ---- per-bucket: count per node, write row_start/dinv, place src-only csr ----
__global__ __launch_bounds__(256) void k_binC(const int* __restrict__ bbase,
                                              const int* __restrict__ tot,
                                              const int* __restrict__ ebuf,
                                              int* __restrict__ row_start,
                                              float* __restrict__ dinv,
                                              int* __restrict__ csr) {
    __shared__ int cnt[64], excl[64], cur[64];
    int b = blockIdx.x, tid = threadIdx.x;
    int n0 = b * 64;
    int base = bbase[b], end = base + tot[b];
    if (tid < 64) cnt[tid] = 0;
    __syncthreads();
    for (int i = base + tid; i < end; i += 256)
        atomicAdd(&cnt[((unsigned)ebuf[i]) >> 17], 1);
    __syncthreads();
    if (tid == 0) {
        int run = 0;
        for (int t = 0; t < 64; ++t) { excl[t] = run; run += cnt[t]; }
    }
    __syncthreads();
    if (tid < 64) {
        int node = n0 + tid;
        if (node < NN) {
            row_start[node] = base + excl[tid];
            dinv[node] = rsqrtf((float)cnt[tid] + 1.0f);
        }
        cur[tid] = base + excl[tid];
    }
    if (b == NBUCK - 1 && tid == 0) row_start[NN] = end;
    __syncthreads();
    for (int i = base + tid; i < end; i += 256) {
        unsigned rec = (unsigned)ebuf[i];
        int pos = atomicAdd(&cur[rec >> 17], 1);
        csr[pos] = (int)(rec & 0x1FFFFu);
    }
}

// ---- layer-1 aggregate (round-0 winner, bit-exact): P[n] = bf16( xb[n]*sn + sum w_e*xb[src_e] ) ----
__global__ __launch_bounds__(256) void k_agg1(const unsigned short* __restrict__ xb,
                                              const float* __restrict__ dinv,
                                              const int* __restrict__ row_start,
                                              const int* __restrict__ csr,
                                              char* __restrict__ P) {
    int node = blockIdx.x * 4 + (threadIdx.x >> 6);   // grid = NN/4 exactly
    int lane = threadIdx.x & 63;
    float dv = dinv[node]; float sn = dv * dv;
    unsigned int sv = ((const unsigned int*)(xb + (size_t)node * 128))[lane];
    float ax = b2f((unsigned short)(sv & 0xFFFF)) * sn;
    float ay = b2f((unsigned short)(sv >> 16)) * sn;
    int base = row_start[node], end = row_start[node + 1];
    for (int i0 = base; i0 < end; i0 += 64) {
        int idx = i0 + lane;
        int s = (idx < end) ? csr[idx] : 0;
        float wv = (idx < end) ? dinv[s] * dv : 0.f;
        int m = min(64, end - i0);
        int j = 0;
        for (; j + 3 < m; j += 4) {
            int   s0 = __shfl(s, j),  s1 = __shfl(s, j + 1);
            int   s2 = __shfl(s, j + 2), s3 = __shfl(s, j + 3);
            float w0 = __shfl(wv, j), w1 = __shfl(wv, j + 1);
            float w2 = __shfl(wv, j + 2), w3 = __shfl(wv, j + 3);
            unsigned int v0 = ((const unsigned int*)(xb + (size_t)s0 * 128))[lane];
            unsigned int v1 = ((const unsigned int*)(xb + (size_t)s1 * 128))[lane];
            unsigned int v2 = ((const unsigned int*)(xb + (size_t)s2 * 128))[lane];
            unsigned int v3 = ((const unsigned int*)(xb + (size_t)s3 * 128))[lane];
            ax = fmaf(b2f((unsigned short)(v0 & 0xFFFF)), w0, ax);
            ay = fmaf(b2f((unsigned short)(v0 >> 16)),    w0, ay);
            ax = fmaf(b2f((unsigned short)(v1 & 0xFFFF)), w1, ax);
            ay = fmaf(b2f((unsigned short)(v1 >> 16)),    w1, ay);
            ax = fmaf(b2f((unsigned short)(v2 & 0xFFFF)), w2, ax);
            ay = fmaf(b2f((unsigned short)(v2 >> 16)),    w2, ay);
            ax = fmaf(b2f((unsigned short)(v3 & 0xFFFF)), w3, ax);
            ay = fmaf(b2f((unsigned short)(v3 >> 16)),    w3, ay);
        }
        for (; j < m; ++j) {
            int s0 = __shfl(s, j);
            float w0 = __shfl(wv, j);
            unsigned int v0 = ((const unsigned int*)(xb + (size_t)s0 * 128))[lane];
            ax = fmaf(b2f((unsigned short)(v0 & 0xFFFF)), w0, ax);
            ay = fmaf(b2f((unsigned short)(v0 >> 16)),    w0, ay);
        }
    }
    unsigned int o = (unsigned int)f2b(ax) | ((unsigned int)f2b(ay) << 16);
    ((unsigned int*)(P + (size_t)node * 256))[lane] = o;
}

// ---- fused GEMM1+GEMM2 (MFMA): t2 = bf16( relu(agg@W1+b1) @ W2 ), in-place ----
__global__ __launch_bounds__(256) void k_gemm12(const float* __restrict__ W1,
                                                const float* __restrict__ b1,
                                                const float* __restrict__ W2,
                                                char* __restrict__ P) {
    __shared__ short Wl1[16384];                    // [ct8][ks4][lane64][j8]
    __shared__ short Wl2[8192];                     // [ct4][ks4][lane64][j8]
    __shared__ __align__(16) short Cl[4][16][128];
    const int tid = threadIdx.x;
    const int w = tid >> 6, lane = tid & 63;
    const int r0 = blockIdx.x * 64;

    for (int i = tid; i < 16384; i += 256) {
        int j = i & 7, l = (i >> 3) & 63, ks = (i >> 9) & 3, ct = i >> 11;
        int k = ks * 32 + ((l >> 4) << 3) + j;
        int c = ct * 16 + (l & 15);
        Wl1[i] = (short)f2b(W1[k * 128 + c]);
    }
    for (int i = tid; i < 8192; i += 256) {
        int j = i & 7, l = (i >> 3) & 63, ks = (i >> 9) & 3, ct = i >> 11;
        int k = ks * 32 + ((l >> 4) << 3) + j;
        int c = ct * 16 + (l & 15);
        Wl2[i] = (short)f2b(W2[k * 64 + c]);
    }
    __syncthreads();

    const int m = r0 + w * 16 + (lane & 15);
    const int quad = lane >> 4;
    const bool mok = (m < NN);
    bf16x8 a[4];
#pragma unroll
    for (int ks = 0; ks < 4; ++ks) {
        if (mok) a[ks] = *(const bf16x8*)(P + (size_t)m * 256 + (ks * 32 + quad * 8) * 2);
        else     a[ks] = bf16x8{0,0,0,0,0,0,0,0};
    }
#pragma unroll
    for (int ct = 0; ct < 8; ++ct) {
        f32x4 c = {0.f, 0.f, 0.f, 0.f};
#pragma unroll
        for (int ks = 0; ks < 4; ++ks) {
            bf16x8 b = *(const bf16x8*)&Wl1[((ct * 4 + ks) * 64 + lane) * 8];
            c = __builtin_amdgcn_mfma_f32_16x16x32_bf16(a[ks], b, c, 0, 0, 0);
        }
        int col = ct * 16 + (lane & 15);
        float bias = b1[col];
#pragma unroll
        for (int r = 0; r < 4; ++r)
            Cl[w][quad * 4 + r][col] = (short)f2b(fmaxf(c[r] + bias, 0.f));
    }
    __syncthreads();
    bf16x8 a2[4];
#pragma unroll
    for (int ks = 0; ks < 4; ++ks)
        a2[ks] = *(const bf16x8*)&Cl[w][lane & 15][ks * 32 + quad * 8];
    __syncthreads();
    short* Ct = &Cl[0][0][0];   // [64 rows][64 cols]
#pragma unroll
    for (int ct = 0; ct < 4; ++ct) {
        f32x4 c = {0.f, 0.f, 0.f, 0.f};
#pragma unroll
        for (int ks = 0; ks < 4; ++ks) {
            bf16x8 b = *(const bf16x8*)&Wl2[((ct * 4 + ks) * 64 + lane) * 8];
            c = __builtin_amdgcn_mfma_f32_16x16x32_bf16(a2[ks], b, c, 0, 0, 0);
        }
        int col = ct * 16 + (lane & 15);
#pragma unroll
        for (int r = 0; r < 4; ++r)
            Ct[(w * 16 + quad * 4 + r) * 64 + col] = (short)f2b(c[r]);
    }
    __syncthreads();
    for (int it = 0; it < 8; ++it) {
        int row = it * 2 + (lane >> 5), u = lane & 31;
        int node = r0 + w * 16 + row;
        if (node < NN)
            *(unsigned int*)(P + (size_t)node * 256 + u * 4) =
                ((const unsigned int*)&Ct[(w * 16 + row) * 64])[u];
    }
}

// ---- layer-2 aggregate + epilogue: 8 neighbor rows PER GATHER INSTRUCTION ----
// Row = 128B = 8 lanes x dwordx4. Lane l: edge slot sub=l>>3, dim chunk dimb=l&7
// (dims dimb*8..dimb*8+7). One uint4 wave-load fetches 8 rows (16 lines).
// Per-dim partials live in 8 lanes; 3-round butterfly reduce at node end.
__global__ __launch_bounds__(256) void k_agg2(const float* __restrict__ dinv,
                                              const int* __restrict__ row_start,
                                              const int* __restrict__ csr,
                                              const char* __restrict__ P,
                                              const float* __restrict__ b2,
                                              float* __restrict__ outp) {
    int node = blockIdx.x * 4 + (threadIdx.x >> 6);   // grid = NN/4 exactly
    int lane = threadIdx.x & 63;
    int sub  = lane >> 3;          // edge slot within group of 8
    int dimb = lane & 7;           // 16B chunk within 128B row
    const uint4* P4 = (const uint4*)P;   // 16 uint4 per 256B slot; first 8 live
    float dv = dinv[node];
    float sn8 = dv * dv * 0.125f;  // exact /8: 8 identical partials sum back to x*sn
    uint4 sv = P4[(size_t)node * 16 + dimb];
    f32x2 a0, a1, a2, a3;
    a0.x = __uint_as_float(sv.x << 16) * sn8;  a0.y = __uint_as_float(sv.x & 0xFFFF0000u) * sn8;
    a1.x = __uint_as_float(sv.y << 16) * sn8;  a1.y = __uint_as_float(sv.y & 0xFFFF0000u) * sn8;
    a2.x = __uint_as_float(sv.z << 16) * sn8;  a2.y = __uint_as_float(sv.z & 0xFFFF0000u) * sn8;
    a3.x = __uint_as_float(sv.w << 16) * sn8;  a3.y = __uint_as_float(sv.w & 0xFFFF0000u) * sn8;
    int base = row_start[node], end = row_start[node + 1];
    if (end > base) {
        for (int c0 = base; c0 < end; c0 += 64) {
            int idx = c0 + lane;
            int cl = min(idx, end - 1);
            int s = csr[cl];
            float wv = (idx < end) ? dinv[s] * dv : 0.f;   // clamp lanes neutralized
            int ng = min(64, end - c0);
            for (int g = 0; g * 8 < ng; ++g) {
                int   sq = __shfl(s,  g * 8 + sub);
                float wq = __shfl(wv, g * 8 + sub);
                uint4 v = P4[(size_t)sq * 16 + dimb];      // 8 rows per instruction
                f32x2 wv2; wv2.x = wq; wv2.y = wq;
                f32x2 xv;
                xv.x = __uint_as_float(v.x << 16); xv.y = __uint_as_float(v.x & 0xFFFF0000u);
                a0 = __builtin_elementwise_fma(xv, wv2, a0);
                xv.x = __uint_as_float(v.y << 16); xv.y = __uint_as_float(v.y & 0xFFFF0000u);
                a1 = __builtin_elementwise_fma(xv, wv2, a1);
                xv.x = __uint_as_float(v.z << 16); xv.y = __uint_as_float(v.z & 0xFFFF0000u);
                a2 = __builtin_elementwise_fma(xv, wv2, a2);
                xv.x = __uint_as_float(v.w << 16); xv.y = __uint_as_float(v.w & 0xFFFF0000u);
                a3 = __builtin_elementwise_fma(xv, wv2, a3);
            }
        }
    }
    // butterfly reduce the 8 edge-slot partials (lanes xor 8,16,32)
#pragma unroll
    for (int mgap = 8; mgap < 64; mgap <<= 1) {
        a0.x += __shfl_xor(a0.x, mgap); a0.y += __shfl_xor(a0.y, mgap);
        a1.x += __shfl_xor(a1.x, mgap); a1.y += __shfl_xor(a1.y, mgap);
        a2.x += __shfl_xor(a2.x, mgap); a2.y += __shfl_xor(a2.y, mgap);
        a3.x += __shfl_xor(a3.x, mgap); a3.y += __shfl_xor(a3.y, mgap);
    }
    if (lane < 8) {
        float4 ba = ((const float4*)b2)[lane * 2];
        float4 bb = ((const float4*)b2)[lane * 2 + 1];
        float4 o0, o1;
        o0.x = a0.x + ba.x; o0.y = a0.y + ba.y; o0.z = a1.x + ba.z; o0.w = a1.y + ba.w;
        o1.x = a2.x + bb.x; o1.y = a2.y + bb.y; o1.z = a3.x + bb.z; o1.w = a3.y + bb.w;
        ((float4*)outp)[(size_t)node * 16 + lane * 2]     = o0;
        ((float4*)outp)[(size_t)node * 16 + lane * 2 + 1] = o1;
    }
}

extern "C" void kernel_launch(void* const* d_in, const int* in_sizes, int n_in,
                              void* d_out, int out_size, void* d_ws, size_t ws_size,
                              hipStream_t stream) {
    const float* x  = (const float*)d_in[0];
    const int*   ei = (const int*)d_in[1];
    const float* W1 = (const float*)d_in[2];
    const float* b1 = (const float*)d_in[3];
    const float* W2 = (const float*)d_in[4];
    const float* b2 = (const float*)d_in[5];
    float* out = (float*)d_out;
    const int* src = ei;
    const int* dst = ei + NE;

    char* ws = (char*)d_ws;
    unsigned short* xb        = (unsigned short*)(ws + 0);
    char*           P         = ws + 25600000;
    int*            ghist     = (int*)(ws + 25600000);   // overlaps P (dead first)
    int*            boffT     = (int*)(ws + 27200512);
    int*            tot       = (int*)(ws + 28801024);
    int*            bbase     = (int*)(ws + 28807276);
    int*            row_start = (int*)(ws + 51200000);
    float*          dinv      = (float*)(ws + 51600004);
    int*            csr       = (int*)(ws + 52000004);
    int*            ebuf      = (int*)(ws + 58400004);

    k_pre  <<<NBXB + NBH, 256, 0, stream>>>(x, xb, dst, ghist);
    k_scanB<<<(NBUCK + 255) / 256, 256, 0, stream>>>(ghist, boffT, tot);
    k_scanT<<<1, 256, 0, stream>>>(tot, bbase);
    k_place<<<NBH, 256, 0, stream>>>(src, dst, bbase, boffT, ebuf);
    k_binC <<<NBUCK, 256, 0, stream>>>(bbase, tot, ebuf, row_start, dinv, csr);

    k_agg1  <<<NN / 4, 256, 0, stream>>>(xb, dinv, row_start, csr, P);
    k_gemm12<<<NBG, 256, 0, stream>>>(W1, b1, W2, P);
    k_agg2  <<<NN / 4, 256, 0, stream>>>(dinv, row_start, csr, P, b2, out);
}